// Round 5
// baseline (473.191 us; speedup 1.0000x reference)
//
#include <hip/hip_runtime.h>
#include <stdint.h>

#define NIMG 32
#define H 1024
#define W 1024
#define BH 73
#define BW 73
#define NCHUNK (NIMG * BH)        // 2336 chunks; chunk = n*73 + by
#define TOTAL (NIMG * BH * BW)    // 170528
#define BS 14                     // block stride
#define KW 16                     // pool window
#define NT 256

#define ST_AGG  0x40000000u       // aggregate published
#define ST_PRE  0x80000000u       // inclusive prefix published
#define ST_RDY  (ST_AGG | ST_PRE)
#define ST_VAL  0x3FFFFFFFu

// Single-dispatch pool + decoupled-lookback scan + scatter.
// Ticket-ordered chunks guarantee lookback forward progress (a chunk's
// predecessors in ticket order already hold tickets => already executing =>
// publish their aggregate unconditionally before any spin).
__global__ __launch_bounds__(NT) void fused_kernel(const float* __restrict__ mask,
                                                   unsigned* __restrict__ status,   // [NCHUNK], zeroed
                                                   unsigned* __restrict__ ticket,   // zeroed
                                                   int* __restrict__ out_idx) {
    int t = threadIdx.x;
    int lane = t & 63;
    int wave = t >> 6;
    __shared__ float colmax[W];
    __shared__ int sred[4];
    __shared__ int schunk;
    __shared__ int sexcl;

    if (t == 0) schunk = (int)atomicAdd(ticket, 1u);
    __syncthreads();
    int chunk = schunk;
    int n  = chunk / BH;
    int by = chunk - n * BH;
    const float* img = mask + (size_t)n * (H * W);

    // ---------------- pool: 16x16 window max, stride 14, pad 1 ----------------
    int y0 = by * BS - 1;
    float4 v[8];
#pragma unroll
    for (int r = 0; r < 8; ++r) {              // rows 0..7, clamped (dup row 0
        int y = y0 + r;                        // is a no-op under max)
        y = (y < 0) ? 0 : y;
        v[r] = ((const float4*)(img + (size_t)y * W))[t];
    }
    float4 acc = v[0];
#pragma unroll
    for (int r = 1; r < 8; ++r) {
        acc.x = fmaxf(acc.x, v[r].x);
        acc.y = fmaxf(acc.y, v[r].y);
        acc.z = fmaxf(acc.z, v[r].z);
        acc.w = fmaxf(acc.w, v[r].w);
    }
#pragma unroll
    for (int r = 0; r < 8; ++r) {              // rows 8..15 (never clamped)
        v[r] = ((const float4*)(img + (size_t)(y0 + 8 + r) * W))[t];
    }
#pragma unroll
    for (int r = 0; r < 8; ++r) {
        acc.x = fmaxf(acc.x, v[r].x);
        acc.y = fmaxf(acc.y, v[r].y);
        acc.z = fmaxf(acc.z, v[r].z);
        acc.w = fmaxf(acc.w, v[r].w);
    }
    ((float4*)colmax)[t] = acc;
    __syncthreads();

    int flag = 0;
    if (t < BW) {
        int x0 = t * BS - 1;
        float m = colmax[x0 < 0 ? 0 : x0];
#pragma unroll
        for (int c = 1; c < KW; ++c) m = fmaxf(m, colmax[x0 + c]);  // in [0,1022]
        flag = (m > 0.5f) ? 1 : 0;
    }
    unsigned long long b = __ballot(flag);
    if (lane == 0) sred[wave] = __popcll(b);
    __syncthreads();
    int count = sred[0] + sred[1] + sred[2] + sred[3];

    // ---------------- publish + decoupled lookback ----------------
    if (t == 0) {
        unsigned pub = ((chunk == 0) ? ST_PRE : ST_AGG) | (unsigned)count;
        __hip_atomic_store(&status[chunk], pub, __ATOMIC_RELEASE, __HIP_MEMORY_SCOPE_AGENT);
        if (chunk == 0) sexcl = 0;
    }
    if (wave == 0 && chunk > 0) {
        int excl = 0;                          // meaningful on lane 0 only
        int j = chunk - 1;
        for (;;) {
            int idx = j - lane;                // lane 0 = closest predecessor
            unsigned s;
            for (;;) {                         // spin until whole window ready
                s = (idx >= 0)
                    ? __hip_atomic_load(&status[idx], __ATOMIC_ACQUIRE, __HIP_MEMORY_SCOPE_AGENT)
                    : ST_PRE;                  // virtual prefix=0 before chunk 0
                unsigned long long rdy = __ballot((s & ST_RDY) != 0);
                if (rdy == ~0ull) break;
            }
            unsigned long long pre = __ballot((s & ST_PRE) != 0);
            int val = (int)(s & ST_VAL);
            int contrib;
            if (pre) {
                int lp = __ffsll((unsigned long long)pre) - 1;  // closest prefix
                contrib = (lane <= lp) ? val : 0;  // aggregates before it + the prefix
            } else {
                contrib = val;                 // all aggregates, keep walking
            }
            contrib += __shfl_down(contrib, 32);
            contrib += __shfl_down(contrib, 16);
            contrib += __shfl_down(contrib, 8);
            contrib += __shfl_down(contrib, 4);
            contrib += __shfl_down(contrib, 2);
            contrib += __shfl_down(contrib, 1);
            excl += contrib;                   // valid on lane 0
            if (pre) break;
            j -= 64;
        }
        if (lane == 0) {
            __hip_atomic_store(&status[chunk], ST_PRE | (unsigned)(excl + count),
                               __ATOMIC_RELEASE, __HIP_MEMORY_SCOPE_AGENT);
            sexcl = excl;
        }
    }
    __syncthreads();
    int excl = sexcl;                          // global exclusive prefix of chunk

    // ---------------- scatter: active triples + tail fill ----------------
    if (t < BW) {
        int wavebase = (wave >= 1) ? sred[0] : 0;   // t<73 spans waves 0,1 only
        int apre = __popcll(b & ((1ull << lane) - 1ull)) + wavebase;
        if (flag) {
            int o = (excl + apre) * 3;
            out_idx[o]     = n;
            out_idx[o + 1] = by;
            out_idx[o + 2] = t;
        } else {
            // fill rows are identical -> any disjoint tiling of the tail works
            int inactive_before = chunk * BW - excl;
            int ipre = t - apre;               // inactive rank within chunk
            int p = TOTAL - inactive_before - (BW - count) + ipre;
            int o = p * 3;
            out_idx[o]     = NIMG;
            out_idx[o + 1] = BH;
            out_idx[o + 2] = BW;
        }
    }
    if (chunk == NCHUNK - 1 && t == 0)
        out_idx[(size_t)TOTAL * 3] = excl + count;  // grand total, for free
}

extern "C" void kernel_launch(void* const* d_in, const int* in_sizes, int n_in,
                              void* d_out, int out_size, void* d_ws, size_t ws_size,
                              hipStream_t stream) {
    const float* mask = (const float*)d_in[0];
    int* out = (int*)d_out;

    unsigned* status = (unsigned*)d_ws;        // [NCHUNK]
    unsigned* ticket = status + NCHUNK;        // [1]

    // ws is poisoned 0xAA (fake ready bits) — zero status + ticket first.
    hipMemsetAsync(d_ws, 0, (NCHUNK + 1) * sizeof(unsigned), stream);
    fused_kernel<<<NCHUNK, NT, 0, stream>>>(mask, status, ticket, out);
}

// Round 6
// 322.345 us; speedup vs baseline: 1.4680x; 1.4680x over previous
//
#include <hip/hip_runtime.h>
#include <hip/hip_cooperative_groups.h>
#include <stdint.h>

namespace cg = cooperative_groups;

#define NIMG 32
#define H 1024
#define W 1024
#define BH 73
#define BW 73
#define NCHUNK (NIMG * BH)        // 2336 chunks; chunk = n*73 + by
#define TOTAL (NIMG * BH * BW)    // 170528
#define BS 14                     // block stride
#define KW 16                     // pool window
#define GRID 1024                 // 4 blocks/CU x 256 CU — co-resident at 32 VGPR
#define NT 256
#define MAXC 3                    // ceil(NCHUNK / GRID)

__device__ __forceinline__ int wave_reduce(int x) {
    x += __shfl_down(x, 32);
    x += __shfl_down(x, 16);
    x += __shfl_down(x, 8);
    x += __shfl_down(x, 4);
    x += __shfl_down(x, 2);
    x += __shfl_down(x, 1);
    return x;                      // valid on lane 0
}

// ---------------------------------------------------------------------------
// Single cooperative dispatch.
// phase 1: per-chunk 16x16/stride-14 max-pool (two batches of 8 independent
//   float4 row loads -> MLP=8, ~32 VGPR), flag in registers, count -> global.
// grid.sync()  (replaces round-5's spin lookback: no coherent-load flood)
// phase 2: per-chunk exclusive prefix = block-parallel sum over the 9 KB
//   L2-hot counts array; ballot rank; scatter active triples + reversed
//   tail fill; last chunk writes the grand total.
// ---------------------------------------------------------------------------
__global__ __launch_bounds__(NT, 4) void coop_kernel(const float* __restrict__ mask,
                                                     int* __restrict__ counts,
                                                     int* __restrict__ out_idx) {
    int t = threadIdx.x;
    int bid = blockIdx.x;
    int lane = t & 63;
    int wave = t >> 6;
    __shared__ float colmax[W];
    __shared__ int sred[4];
    __shared__ int bcnt[4];

    int flag[MAXC];

    // ---------------- phase 1: pool ----------------
    for (int it = 0; it < MAXC; ++it) {
        int chunk = bid + it * GRID;          // block-uniform condition
        flag[it] = 0;
        if (chunk < NCHUNK) {
            int n = chunk / BH;
            int by = chunk - n * BH;
            const float* img = mask + (size_t)n * (H * W);
            int y0 = by * BS - 1;
            float4 v[8];
#pragma unroll
            for (int r = 0; r < 8; ++r) {      // rows 0..7, clamped (dup row 0
                int y = y0 + r;                //  is a no-op under max)
                y = (y < 0) ? 0 : y;
                v[r] = ((const float4*)(img + (size_t)y * W))[t];
            }
            float4 acc = v[0];
#pragma unroll
            for (int r = 1; r < 8; ++r) {
                acc.x = fmaxf(acc.x, v[r].x);
                acc.y = fmaxf(acc.y, v[r].y);
                acc.z = fmaxf(acc.z, v[r].z);
                acc.w = fmaxf(acc.w, v[r].w);
            }
#pragma unroll
            for (int r = 0; r < 8; ++r) {      // rows 8..15 (never clamped)
                v[r] = ((const float4*)(img + (size_t)(y0 + 8 + r) * W))[t];
            }
#pragma unroll
            for (int r = 0; r < 8; ++r) {
                acc.x = fmaxf(acc.x, v[r].x);
                acc.y = fmaxf(acc.y, v[r].y);
                acc.z = fmaxf(acc.z, v[r].z);
                acc.w = fmaxf(acc.w, v[r].w);
            }
            __syncthreads();                   // colmax reuse guard
            ((float4*)colmax)[t] = acc;
            __syncthreads();
            if (t < BW) {
                int x0 = t * BS - 1;
                float m = colmax[x0 < 0 ? 0 : x0];
#pragma unroll
                for (int c = 1; c < KW; ++c) m = fmaxf(m, colmax[x0 + c]);
                flag[it] = (m > 0.5f) ? 1 : 0;
            }
            unsigned long long b = __ballot(flag[it]);
            if (lane == 0) sred[wave] = __popcll(b);
            __syncthreads();
            if (t == 0) counts[chunk] = sred[0] + sred[1] + sred[2] + sred[3];
        }
    }

    cg::this_grid().sync();

    // ---------------- phase 2: prefix + scatter ----------------
    for (int it = 0; it < MAXC; ++it) {
        int chunk = bid + it * GRID;
        if (chunk >= NCHUNK) break;           // block-uniform
        int n = chunk / BH;
        int by = chunk - n * BH;
        // exclusive prefix: block-parallel sum of counts[0..chunk)
        int local = 0;
        for (int i = t; i < chunk; i += NT) local += counts[i];
        local = wave_reduce(local);
        __syncthreads();                      // sred/bcnt reuse guard
        if (lane == 0) sred[wave] = local;
        unsigned long long b = __ballot(flag[it]);
        if (lane == 0) bcnt[wave] = __popcll(b);
        __syncthreads();
        int excl = sred[0] + sred[1] + sred[2] + sred[3];
        int count = bcnt[0] + bcnt[1];        // flags only exist for t<73
        if (t < BW) {
            int apre = __popcll(b & ((1ull << lane) - 1ull)) + (wave == 1 ? bcnt[0] : 0);
            if (flag[it]) {
                int o = (excl + apre) * 3;
                out_idx[o]     = n;
                out_idx[o + 1] = by;
                out_idx[o + 2] = t;
            } else {
                // fill rows identical -> any disjoint tail tiling works
                int inactive_before = chunk * BW - excl;
                int ipre = t - apre;          // inactive rank within chunk
                int p = TOTAL - inactive_before - (BW - count) + ipre;
                int o = p * 3;
                out_idx[o]     = NIMG;
                out_idx[o + 1] = BH;
                out_idx[o + 2] = BW;
            }
        }
        if (chunk == NCHUNK - 1 && t == 0)
            out_idx[(size_t)TOTAL * 3] = excl + count;   // grand total
    }
}

// ---------------------------------------------------------------------------
// Fallback path (round-4 proven kernels) in case cooperative launch fails.
// ---------------------------------------------------------------------------
__global__ __launch_bounds__(256) void pool_kernel(const float* __restrict__ mask,
                                                   uint8_t* __restrict__ flags,
                                                   int* __restrict__ counts,
                                                   int* __restrict__ out_idx) {
    int chunk = blockIdx.x;
    int n  = chunk / BH;
    int by = chunk - n * BH;
    const float* img = mask + (size_t)n * (H * W);
    int t = threadIdx.x;
    int lane = t & 63;
    int wave = t >> 6;
    __shared__ float colmax[W];
    __shared__ int sred[4];

    int y0 = by * BS - 1;
    float4 v[8];
#pragma unroll
    for (int r = 0; r < 8; ++r) {
        int y = y0 + r;
        y = (y < 0) ? 0 : y;
        v[r] = ((const float4*)(img + (size_t)y * W))[t];
    }
    float4 acc = v[0];
#pragma unroll
    for (int r = 1; r < 8; ++r) {
        acc.x = fmaxf(acc.x, v[r].x);
        acc.y = fmaxf(acc.y, v[r].y);
        acc.z = fmaxf(acc.z, v[r].z);
        acc.w = fmaxf(acc.w, v[r].w);
    }
#pragma unroll
    for (int r = 0; r < 8; ++r) {
        v[r] = ((const float4*)(img + (size_t)(y0 + 8 + r) * W))[t];
    }
#pragma unroll
    for (int r = 0; r < 8; ++r) {
        acc.x = fmaxf(acc.x, v[r].x);
        acc.y = fmaxf(acc.y, v[r].y);
        acc.z = fmaxf(acc.z, v[r].z);
        acc.w = fmaxf(acc.w, v[r].w);
    }
    ((float4*)colmax)[t] = acc;
    __syncthreads();

    int flag = 0;
    if (t < BW) {
        int x0 = t * BS - 1;
        float m = colmax[x0 < 0 ? 0 : x0];
#pragma unroll
        for (int c = 1; c < KW; ++c) m = fmaxf(m, colmax[x0 + c]);
        flag = (m > 0.5f) ? 1 : 0;
        flags[chunk * BW + t] = (uint8_t)flag;
    }
    if (t < BW * 3) {
        int p = chunk * (BW * 3) + t;
        out_idx[p] = ((t % 3) == 0) ? NIMG : BH;
    }
    unsigned long long b = __ballot(flag);
    if (lane == 0) sred[wave] = __popcll(b);
    __syncthreads();
    if (t == 0) counts[chunk] = sred[0] + sred[1] + sred[2] + sred[3];
}

__global__ __launch_bounds__(128) void scatter_kernel(const uint8_t* __restrict__ flags,
                                                      const int* __restrict__ counts,
                                                      int* __restrict__ out_idx) {
    int chunk = blockIdx.x;
    int n  = chunk / BH;
    int by = chunk - n * BH;
    int t = threadIdx.x;
    int lane = t & 63;
    int wave = t >> 6;
    __shared__ int sred[2];
    __shared__ int w0cnt;

    int flag = (t < BW) ? (int)flags[chunk * BW + t] : 0;
    int local = 0;
    for (int i = t; i < chunk; i += 128) local += counts[i];
    local = wave_reduce(local);
    if (lane == 0) sred[wave] = local;
    unsigned long long b = __ballot(flag);
    if (t == 0) w0cnt = __popcll(b);
    __syncthreads();
    int cbase = sred[0] + sred[1];
    int pos = __popcll(b & ((1ull << lane) - 1ull)) + ((t >= 64) ? w0cnt : 0);
    if (flag) {
        int o = (cbase + pos) * 3;
        out_idx[o]     = n;
        out_idx[o + 1] = by;
        out_idx[o + 2] = t;
    }
    if (chunk == 0) {
        int tot = 0;
        for (int i = t; i < NCHUNK; i += 128) tot += counts[i];
        tot = wave_reduce(tot);
        __syncthreads();
        if (lane == 0) sred[wave] = tot;
        __syncthreads();
        if (t == 0) out_idx[(size_t)TOTAL * 3] = sred[0] + sred[1];
    }
}

extern "C" void kernel_launch(void* const* d_in, const int* in_sizes, int n_in,
                              void* d_out, int out_size, void* d_ws, size_t ws_size,
                              hipStream_t stream) {
    const float* mask = (const float*)d_in[0];
    int* out = (int*)d_out;

    int* counts = (int*)d_ws;                           // [NCHUNK]
    uint8_t* flags = (uint8_t*)(counts + NCHUNK);       // fallback only

    void* args[] = {(void*)&mask, (void*)&counts, (void*)&out};
    hipError_t err = hipLaunchCooperativeKernel((void*)coop_kernel, dim3(GRID),
                                                dim3(NT), args, 0, stream);
    if (err != hipSuccess) {
        // proven two-kernel path (round 4)
        pool_kernel<<<NCHUNK, 256, 0, stream>>>(mask, flags, counts, out);
        scatter_kernel<<<NCHUNK, 128, 0, stream>>>(flags, counts, out);
    }
}